// Round 11
// baseline (206.588 us; speedup 1.0000x reference)
//
#include <hip/hip_runtime.h>

// STKBranch double-softmax attention, f16-MFMA 2-pass, R21:
//   Base = R20 (key-split 1024-thr blocks, 2 groups x 8 waves; main 89.5us,
//   occ 71%, no spill; bench gated by prep ~15us of which ~half is launch
//   overhead). Change: PREP IS V-ONLY (transpose is the only thing that needs
//   a pre-pass). K is staged f32->f16 in-kernel (R17's proven path):
//   - prep traffic 50->25 MB (~4-5us dispatch), same single extra launch.
//   - main K staging: 2x float4 load + pk + 2x uint2 LDS write per thread per
//     tile. Register peak (pass 2): 12 staging + 8 aq + 20 O/Oe + 4 pfr ~ 54
//     < 64 cap. Pass 1 keeps the 2-tile super-buffer via idle Vt (8 barriers,
//     16 staging regs live but no O/V state there).
//   - everything else = R20: swapped QK^T, P in regs as PV B-frag, permuted
//     Vt cols -> b128 PV reads, pair interleave, ones-MFMA l2, setprio,
//     QS=72 floors, s1/O cross-group merges.
// Math: L = scale*q@k^T ; w = softmax(2L) ; attn = softmax(L*w) ; out = attn@v
// |L| <= ~7 -> no max-subtraction. B=4 H=8 N=2048 D=64 fp32 io.

typedef _Float16 f16;
typedef f16 f16x8 __attribute__((ext_vector_type(8)));
typedef f16 f16x4 __attribute__((ext_vector_type(4)));
typedef float f32x4 __attribute__((ext_vector_type(4)));

#define MFMA32(a, b, c) __builtin_amdgcn_mfma_f32_16x16x32_f16((a), (b), (c), 0, 0, 0)
#define MFMA16(a, b, c) __builtin_amdgcn_mfma_f32_16x16x16f16((a), (b), (c), 0, 0, 0)
#define EXP2(x) __builtin_amdgcn_exp2f(x)   // v_exp_f32: D = 2^S0

#define N_CTX 2048
#define DH 64
#define KT 64
#define NKT_G 16          // tiles per key-group (1024 keys / KT)
#define ROWS 128          // 8 waves x 16 q-rows (per group)
#define QS 72             // LDS row stride (f16): 144 B (bank-floor, proven)
#define KSB (KT * QS)     // 4608 f16 = one Ks/Vt buffer (9216 B)
// smem carve (f16): KsG0 dbuf | KsG1 dbuf | VtG0 dbuf | VtG1 dbuf | sred(f32)
#define SMEM_BYTES (4 * 2 * KSB * 2 + 2048)   // 73728 + 2048 = 75776 B

#define C2 2.885390081777927f    // 2*log2(e), folded into Q fragments

__device__ inline unsigned pk(float a, float b) {
    typedef __fp16 fp16x2_t __attribute__((ext_vector_type(2)));
    union { fp16x2_t v; unsigned u; } x;
    x.v = __builtin_amdgcn_cvt_pkrtz(a, b);
    return x.u;
}

// ---------------- pre-pass: V -> f16 transposed workspace ----------------
// wsV[bh*131072 + t*4096 + d*64 + c], c(key)=((key>>2)&3)*16+((key>>4)&3)*4+(key&3)
__global__ __launch_bounds__(256)
void stk_prep(const float* __restrict__ vg, f16* __restrict__ wsV) {
    __shared__ f16 lds[DH * QS];          // [d][c], stride 72
    const int tid = threadIdx.x;
    const int bh = blockIdx.x >> 5, t = blockIdx.x & 31;
    // read: pair p = tid>>3 (keys 2p,2p+1), dseg = tid&7 (d = dseg*8..+7)
    const int p = tid >> 3, dseg = tid & 7, d0 = dseg * 8;
    const int c0 = ((p >> 1) & 3) * 16 + ((p >> 3) & 3) * 4 + (p & 1) * 2;
    const float* base = vg + (((size_t)(bh * 2048 + t * 64 + 2 * p)) << 6) + d0;
    float4 a0 = *(const float4*)(base);
    float4 a1 = *(const float4*)(base + 4);
    float4 b0 = *(const float4*)(base + 64);
    float4 b1 = *(const float4*)(base + 68);
    #pragma unroll
    for (int j = 0; j < 4; ++j) {
        *(unsigned*)&lds[(d0 + j) * QS + c0] =
            pk(((const float*)&a0)[j], ((const float*)&b0)[j]);
        *(unsigned*)&lds[(d0 + 4 + j) * QS + c0] =
            pk(((const float*)&a1)[j], ((const float*)&b1)[j]);
    }
    __syncthreads();
    // write out: d = tid>>2, cs = tid&3 -> 32B contiguous per thread
    const int d = tid >> 2, cs = tid & 3;
    f16x8 r0 = *(const f16x8*)&lds[d * QS + cs * 16];
    f16x8 r1 = *(const f16x8*)&lds[d * QS + cs * 16 + 8];
    f16* dst = wsV + ((((size_t)bh * 32 + t) << 6) + d) * 64 + cs * 16;
    *(f16x8*)(dst) = r0;
    *(f16x8*)(dst + 8) = r1;
}

// ---------------- main kernel ----------------
__global__ __launch_bounds__(1024, 8)
void stk_attn_mfma(const float* __restrict__ qg, const float* __restrict__ kg,
                   const f16* __restrict__ wsV, const float* __restrict__ sg,
                   float* __restrict__ og) {
    extern __shared__ f16 smem[];

    const int tid  = threadIdx.x;
    const int wv   = tid >> 6;        // 0..15
    const int grp  = wv >> 3;         // key-group 0/1
    const int wv7  = wv & 7;          // wave within group
    const int lane = tid & 63;
    const int l15  = lane & 15;
    const int q4   = lane >> 4;
    const int tg   = (wv7 << 6) | lane;  // tid within group, 0..511
    const int bh   = blockIdx.x & 31; // XCD swizzle: head h -> blocks h+32j -> XCD h%8
    const int q0   = (blockIdx.x >> 5) * ROWS;
    const float scale2 = sg[0] * C2;  // fold 2*log2e: acc = 2L*log2e

    const float* qb = qg + (size_t)bh * N_CTX * DH;
    float*       ob = og + (size_t)bh * N_CTX * DH;
    const float* kbg = kg + ((size_t)bh * N_CTX + grp * (NKT_G * KT)) * DH;
    const f16* wsVh = wsV + ((size_t)bh << 17);   // *131072
    const int T0 = grp * NKT_G;       // group's first tile (of 32 per head)

    // ---- Q fragments direct from global: row q0 + wv7*16 + l15 ----
    f16x8 aq[2];
    {
        const float* qrow = qb + (size_t)(q0 + wv7 * 16 + l15) * DH;
        #pragma unroll
        for (int kc = 0; kc < 2; ++kc) {
            float4 a0 = *(const float4*)&qrow[kc * 32 + q4 * 8];
            float4 a1 = *(const float4*)&qrow[kc * 32 + q4 * 8 + 4];
            union { f16x8 h; unsigned u[4]; } A;
            A.u[0] = pk(a0.x * scale2, a0.y * scale2);
            A.u[1] = pk(a0.z * scale2, a0.w * scale2);
            A.u[2] = pk(a1.x * scale2, a1.y * scale2);
            A.u[3] = pk(a1.z * scale2, a1.w * scale2);
            aq[kc] = A.h;
        }
    }

    // group-private LDS bases
    f16* const ksBase = smem + grp * (2 * KSB);
    f16* const vtBase = smem + 2 * (2 * KSB) + grp * (2 * KSB);
    float* const sred = (float*)(smem + 4 * (2 * KSB));     // 512 floats
    float* const obuf = (float*)smem;                       // epilogue reuse

    // staging offsets: idx = it*512 + tg
    int kofs[2], gofs[2];
    #pragma unroll
    for (int it = 0; it < 2; ++it) {
        int idx = it * 512 + tg;
        gofs[it] = (idx >> 4) * DH + (idx & 15) * 4;   // global f32 offset in tile
        kofs[it] = (idx >> 4) * QS + (idx & 15) * 4;   // LDS f16 offset in buffer
    }
    const int sofs = tg * 8;                          // wsV tile read offset (f16)
    const int wofs = (tg >> 3) * QS + (tg & 7) * 8;   // V LDS b128 write offset

    const f16* const ks_r = ksBase + l15 * QS + q4 * 8;   // QK^T A-frag: K row l15
    const f16* const ksrB = vtBase + l15 * QS + q4 * 8;   // pass-1 alt super-buffer
    const f16* const vt_r = vtBase + l15 * QS + q4 * 16;  // PV A-frags: 16 f16

    // ===== PASS 1: s1 = sum_k exp(2L); 2-tile super-buffers, K f32->f16 =====
    float s1 = 0.f;
    float4 kra[2], krb[2];
    #pragma unroll
    for (int it = 0; it < 2; ++it) {
        kra[it] = *(const float4*)&kbg[gofs[it]];                 // tile 0
        krb[it] = *(const float4*)&kbg[KT * DH + gofs[it]];       // tile 1
    }
    #pragma unroll
    for (int it = 0; it < 2; ++it) {
        *(uint2*)&ksBase[kofs[it]] =
            make_uint2(pk(kra[it].x, kra[it].y), pk(kra[it].z, kra[it].w));
        *(uint2*)&ksBase[KSB + kofs[it]] =
            make_uint2(pk(krb[it].x, krb[it].y), pk(krb[it].z, krb[it].w));
    }
    #pragma unroll
    for (int it = 0; it < 2; ++it) {
        kra[it] = *(const float4*)&kbg[2 * KT * DH + gofs[it]];   // tile 2
        krb[it] = *(const float4*)&kbg[3 * KT * DH + gofs[it]];   // tile 3
    }
    __syncthreads();

    for (int st = 0; st < 8; ++st) {
        f16* const nxtb = (st & 1) ? ksBase : vtBase;
        const f16* const crd = (st & 1) ? ksrB : ks_r;
        // write super-tile st+1 into the other super-buffer
        #pragma unroll
        for (int it = 0; it < 2; ++it) {
            *(uint2*)&nxtb[kofs[it]] =
                make_uint2(pk(kra[it].x, kra[it].y), pk(kra[it].z, kra[it].w));
            *(uint2*)&nxtb[KSB + kofs[it]] =
                make_uint2(pk(krb[it].x, krb[it].y), pk(krb[it].z, krb[it].w));
        }
        {   // prefetch super-tile st+2 (clamped)
            int tn = (st + 2 < 8) ? st + 2 : 7;
            #pragma unroll
            for (int it = 0; it < 2; ++it) {
                kra[it] = *(const float4*)&kbg[(size_t)(2 * tn) * KT * DH + gofs[it]];
                krb[it] = *(const float4*)&kbg[(size_t)(2 * tn + 1) * KT * DH + gofs[it]];
            }
        }
        __builtin_amdgcn_s_setprio(1);
        #pragma unroll
        for (int kgi = 0; kgi < 8; ++kgi) {
            f16x8 b0 = *(const f16x8*)&crd[kgi * 16 * QS];
            f16x8 b1 = *(const f16x8*)&crd[kgi * 16 * QS + 32];
            f32x4 acc = {0.f, 0.f, 0.f, 0.f};
            acc = MFMA32(b0, aq[0], acc);   // swapped: C[key][q], lane q = l15
            acc = MFMA32(b1, aq[1], acc);
            s1 += (EXP2(acc[0]) + EXP2(acc[1])) + (EXP2(acc[2]) + EXP2(acc[3]));
        }
        __builtin_amdgcn_s_setprio(0);
        __syncthreads();
    }
    // reduce across q4 partitions, then across key-groups via sred
    s1 += __shfl_xor(s1, 16, 64);
    s1 += __shfl_xor(s1, 32, 64);
    if (lane < 16) sred[(grp << 7) + (wv7 << 4) + lane] = s1;
    __syncthreads();
    s1 += sred[((grp ^ 1) << 7) + (wv7 << 4) + l15];
    const float inv1 = 0.5f / s1;    // e2 = exp2((acc*e1) * 0.5/s1)  [acc = 2L*log2e]

    // =============== PASS 2: e2, O^T += V^T P^T, l2 via ones-MFMA ===============
    f32x4 O[4];
    #pragma unroll
    for (int dt = 0; dt < 4; ++dt) O[dt] = (f32x4){0.f, 0.f, 0.f, 0.f};
    f32x4 Oe = {0.f, 0.f, 0.f, 0.f};
    const f16x4 ones = {(f16)1.f, (f16)1.f, (f16)1.f, (f16)1.f};

    f16* const ks_w = ksBase;
    f16* const vt_w = vtBase;
    f16x8 vrh;
    #pragma unroll
    for (int it = 0; it < 2; ++it)
        kra[it] = *(const float4*)&kbg[gofs[it]];                 // K(0) f32
    vrh = *(const f16x8*)&wsVh[(size_t)T0 * 4096 + sofs];         // V(0) f16
    #pragma unroll
    for (int it = 0; it < 2; ++it)
        *(uint2*)&ks_w[kofs[it]] =
            make_uint2(pk(kra[it].x, kra[it].y), pk(kra[it].z, kra[it].w));
    *(f16x8*)&vt_w[wofs] = vrh;
    #pragma unroll
    for (int it = 0; it < 2; ++it)
        kra[it] = *(const float4*)&kbg[KT * DH + gofs[it]];       // K(1)
    vrh = *(const f16x8*)&wsVh[(size_t)(T0 + 1) * 4096 + sofs];   // V(1)
    __syncthreads();

    for (int kt = 0; kt < NKT_G; ++kt) {
        const int cur = (kt & 1) * KSB, nxt = KSB - cur;
        #pragma unroll
        for (int it = 0; it < 2; ++it)
            *(uint2*)&ks_w[nxt + kofs[it]] =
                make_uint2(pk(kra[it].x, kra[it].y), pk(kra[it].z, kra[it].w));
        *(f16x8*)&vt_w[nxt + wofs] = vrh;
        { int tn = (kt + 2 < NKT_G) ? kt + 2 : NKT_G - 1;
          #pragma unroll
          for (int it = 0; it < 2; ++it)
              kra[it] = *(const float4*)&kbg[(size_t)tn * KT * DH + gofs[it]];
          vrh = *(const f16x8*)&wsVh[(size_t)(T0 + tn) * 4096 + sofs]; }
        // per kgi-PAIR: softmax(2p), softmax(2p+1) -> PV(pair p) via b128 V-frags
        __builtin_amdgcn_s_setprio(1);
        #pragma unroll
        for (int p = 0; p < 2; ++p) {
            f16x4 pfr[2];
            #pragma unroll
            for (int h = 0; h < 2; ++h) {
                const int kgi = p * 2 + h;
                f16x8 b0 = *(const f16x8*)&ks_r[cur + kgi * 16 * QS];
                f16x8 b1 = *(const f16x8*)&ks_r[cur + kgi * 16 * QS + 32];
                f32x4 acc = {0.f, 0.f, 0.f, 0.f};
                acc = MFMA32(b0, aq[0], acc);
                acc = MFMA32(b1, aq[1], acc);
                float e2r[4];
                #pragma unroll
                for (int r = 0; r < 4; ++r) {
                    float a  = acc[r];
                    float e1 = EXP2(a);
                    e2r[r] = EXP2((a * e1) * inv1);
                }
                union { f16x4 hh; unsigned u[2]; } P;
                P.u[0] = pk(e2r[0], e2r[1]);
                P.u[1] = pk(e2r[2], e2r[3]);
                pfr[h] = P.hh;
                Oe = MFMA16(ones, pfr[h], Oe);
            }
            #pragma unroll
            for (int dt = 0; dt < 4; ++dt) {
                f16x8 av = *(const f16x8*)&vt_r[cur + dt * 16 * QS + p * 8];
                f16x4 alo = __builtin_shufflevector(av, av, 0, 1, 2, 3);
                f16x4 ahi = __builtin_shufflevector(av, av, 4, 5, 6, 7);
                O[dt] = MFMA16(alo, pfr[0], O[dt]);
                O[dt] = MFMA16(ahi, pfr[1], O[dt]);
            }
        }
        __builtin_amdgcn_s_setprio(0);
        __syncthreads();   // swap: protects Ks/Vt cur<->nxt
    }

    // ---- cross-group merge of O/Oe via dead Ks/Vt LDS; group 0 writes ----
    const int rec = tg * 20;   // 20 f32/thread, 16B-aligned (80 B)
    if (grp) {
        #pragma unroll
        for (int dt = 0; dt < 4; ++dt)
            *(f32x4*)&obuf[rec + dt * 4] = O[dt];
        obuf[rec + 16] = Oe[0];
    }
    __syncthreads();
    if (!grp) {
        #pragma unroll
        for (int dt = 0; dt < 4; ++dt)
            O[dt] += *(const f32x4*)&obuf[rec + dt * 4];
        const float invl2 = 1.0f / (Oe[0] + obuf[rec + 16]);
        const size_t orow = (size_t)(q0 + wv7 * 16 + l15) * DH;
        #pragma unroll
        for (int dt = 0; dt < 4; ++dt) {
            float4 o;
            o.x = O[dt][0] * invl2;
            o.y = O[dt][1] * invl2;
            o.z = O[dt][2] * invl2;
            o.w = O[dt][3] * invl2;
            *(float4*)&ob[orow + dt * 16 + q4 * 4] = o;
        }
    }
}

extern "C" void kernel_launch(void* const* d_in, const int* in_sizes, int n_in,
                              void* d_out, int out_size, void* d_ws, size_t ws_size,
                              hipStream_t stream) {
    const float* q = (const float*)d_in[0];
    const float* k = (const float*)d_in[1];
    const float* v = (const float*)d_in[2];
    const float* s = (const float*)d_in[3];
    float* out = (float*)d_out;
    f16* wsV = (f16*)d_ws;                       // 8 MB
    stk_prep<<<dim3(1024), dim3(256), 0, stream>>>(v, wsV);
    dim3 grid(32 * 16);   // bh = blockIdx&31 (XCD swizzle), q-tile = blockIdx>>5
    stk_attn_mfma<<<grid, 1024, SMEM_BYTES, stream>>>(q, k, wsV, s, out);
}